// Round 4
// baseline (767.390 us; speedup 1.0000x reference)
//
#include <hip/hip_runtime.h>
#include <cstdint>

// ---------------- problem constants (fixed by the reference) ----------------
#define N_NODES   50000
#define N_EDGES   800000
#define N_GRAPHS  256
#define DIM       256
#define MASK_WORDS 400000           // (N_NODES*DIM)/32 packed keep-bits

// ---------------- threefry2x32, key = (0, 42)  (jax.random.key(42)) --------
__device__ __forceinline__ uint32_t rotl32(uint32_t x, int n) {
    return (x << n) | (x >> (32 - n));
}

__device__ __forceinline__ void threefry2x32_k42(uint32_t& x0, uint32_t& x1) {
    const uint32_t ks0 = 0u, ks1 = 42u, ks2 = 0x1BD11BDAu ^ 0u ^ 42u;
    x0 += ks0; x1 += ks1;
#define TF_R(r) { x0 += x1; x1 = rotl32(x1, (r)); x1 ^= x0; }
    TF_R(13) TF_R(15) TF_R(26) TF_R(6)   x0 += ks1; x1 += ks2 + 1u;
    TF_R(17) TF_R(29) TF_R(16) TF_R(24)  x0 += ks2; x1 += ks0 + 2u;
    TF_R(13) TF_R(15) TF_R(26) TF_R(6)   x0 += ks0; x1 += ks1 + 3u;
    TF_R(17) TF_R(29) TF_R(16) TF_R(24)  x0 += ks1; x1 += ks2 + 4u;
    TF_R(13) TF_R(15) TF_R(26) TF_R(6)   x0 += ks2; x1 += ks0 + 5u;
#undef TF_R
}

// Packed dropout keep-mask — PARTITIONABLE threefry (modern JAX default):
// for element i: (o0,o1) = threefry2x32(key, hi32(i)=0, lo32(i)=i),
// draw = o0 ^ o1, uniform u = draw[31:9]/2^23, keep <=> u<0.5 <=> MSB(draw)==0.
__global__ __launch_bounds__(256) void mask_kernel(unsigned* __restrict__ mask) {
    int t = blockIdx.x * 256 + threadIdx.x;
    if (t >= MASK_WORDS) return;
    unsigned m = 0u;
    uint32_t base = (uint32_t)t * 32u;
    #pragma unroll 4
    for (int s = 0; s < 32; ++s) {
        uint32_t x0 = 0u;                 // hi half of 64-bit counter (size < 2^32)
        uint32_t x1 = base + (uint32_t)s; // lo half = element index
        threefry2x32_k42(x0, x1);
        uint32_t draw = x0 ^ x1;          // 32-bit xor-fold (partitionable path)
        m |= ((draw >> 31) ^ 1u) << s;
    }
    mask[t] = m;
}

// ---------------- int64-vs-int32 delivery auto-detection ----------------
// If the harness delivers int64 data unconverted, every odd int32 word is the
// zero hi-half of a small nonnegative value. Probes stay within the int32-
// interpretation bounds of each buffer so neither mode reads OOB.
// flags[0]=1 iff edge_index is int64-delivered; flags[1]=1 iff batch is.
__global__ void detect_kernel(const int* __restrict__ ei,
                              const int* __restrict__ batch,
                              int* __restrict__ flags) {
    if (threadIdx.x != 0 || blockIdx.x != 0) return;
    int z = 0;
    #pragma unroll
    for (int k = 1; k < 33; k += 2) z |= ei[k];       // int32: random src values
    flags[0] = (z == 0) ? 1 : 0;
    int z2 = batch[25001] | batch[30003] | batch[40005] | batch[49999];
    flags[1] = (z2 == 0) ? 1 : 0;                     // int32: mid/late graph ids
}

// ---------------- degree histogram ----------------
__global__ __launch_bounds__(256) void edge_count_kernel(const int* __restrict__ ei,
                                                         const int* __restrict__ flags,
                                                         int* __restrict__ cnt) {
    int e = blockIdx.x * 256 + threadIdx.x;   // grid sized exactly N_EDGES
    int d = flags[0] ? ei[2 * (N_EDGES + e)] : ei[N_EDGES + e];
    atomicAdd(&cnt[d], 1);
}

// ---------------- exclusive scan of cnt -> row_ptr, plus dis = 1/sqrt(deg+1)
__global__ __launch_bounds__(256) void scan_nodes_kernel(const int* __restrict__ cnt,
                                                         int* __restrict__ row_ptr,
                                                         float* __restrict__ dis) {
    __shared__ int ssum[256];
    __shared__ int sexcl[257];
    const int CH = (N_NODES + 255) / 256;   // 196
    int t = threadIdx.x;
    int base = t * CH;
    int sum = 0;
    for (int i = 0; i < CH; ++i) {
        int idx = base + i;
        if (idx < N_NODES) sum += cnt[idx];
    }
    ssum[t] = sum;
    __syncthreads();
    if (t == 0) {
        int run = 0;
        for (int i = 0; i < 256; ++i) { sexcl[i] = run; run += ssum[i]; }
        sexcl[256] = run;
    }
    __syncthreads();
    int run = sexcl[t];
    for (int i = 0; i < CH; ++i) {
        int idx = base + i;
        if (idx < N_NODES) {
            int v = cnt[idx];
            row_ptr[idx] = run;
            run += v;
            dis[idx] = 1.0f / sqrtf((float)v + 1.0f);
        }
    }
    if (t == 0) row_ptr[N_NODES] = sexcl[256];
}

// ---------------- CSR fill: (src, norm) records grouped by dst ----------------
__global__ __launch_bounds__(256) void csr_fill_kernel(const int* __restrict__ ei,
                                                       const int* __restrict__ flags,
                                                       const int* __restrict__ row_ptr,
                                                       int* __restrict__ cur,
                                                       const float* __restrict__ dis,
                                                       int2* __restrict__ recs) {
    int e = blockIdx.x * 256 + threadIdx.x;   // grid sized exactly N_EDGES
    int f = flags[0];
    int s = f ? ei[2 * e] : ei[e];
    int d = f ? ei[2 * (N_EDGES + e)] : ei[N_EDGES + e];
    int pos = row_ptr[d] + atomicAdd(&cur[d], 1);
    float w = dis[s] * dis[d];
    recs[pos] = make_int2(s, __float_as_int(w));
}

// ---------------- graph_ptr via binary search on sorted batch ----------------
__global__ __launch_bounds__(512) void graph_ptr_kernel(const int* __restrict__ batch,
                                                        const int* __restrict__ flags,
                                                        int* __restrict__ gptr) {
    int t = threadIdx.x;
    if (t > N_GRAPHS) return;
    int f = flags[1];
    int lo = 0, hi = N_NODES;          // first index with batch[idx] >= t
    while (lo < hi) {
        int mid = (lo + hi) >> 1;
        int v = f ? batch[2 * mid] : batch[mid];
        if (v < t) lo = mid + 1; else hi = mid;
    }
    gptr[t] = lo;
}

// ---------------- f32 tiled GEMM: out[n][j] = sum_k A[n][k]*Wm[k][j] + b[j] --
// 64x64 tile, BK=32, 256 threads, 4x4 per thread.
__global__ __launch_bounds__(256) void lin_kernel(const float* __restrict__ A,
                                                  const float* __restrict__ Wm,
                                                  const float* __restrict__ bias,
                                                  float* __restrict__ out) {
    __shared__ float As[32][68];   // transposed: As[k][m], stride 68 keeps 16B align
    __shared__ float Bs[32][68];   // Bs[k][n]
    int tid = threadIdx.x;
    int row0 = blockIdx.x * 64;
    int col0 = blockIdx.y * 64;
    int tx = tid & 15, ty = tid >> 4;
    float c[4][4] = {};

    for (int k0 = 0; k0 < DIM; k0 += 32) {
        #pragma unroll
        for (int rep = 0; rep < 2; ++rep) {   // A: 64 rows x 32 cols
            int r = (tid >> 3) + rep * 32;
            int c4 = (tid & 7) * 4;
            int grow = row0 + r;
            float4 v = (grow < N_NODES)
                ? *reinterpret_cast<const float4*>(A + (size_t)grow * DIM + k0 + c4)
                : make_float4(0.f, 0.f, 0.f, 0.f);
            As[c4 + 0][r] = v.x; As[c4 + 1][r] = v.y;
            As[c4 + 2][r] = v.z; As[c4 + 3][r] = v.w;
        }
        #pragma unroll
        for (int rep = 0; rep < 2; ++rep) {   // B: 32 rows x 64 cols
            int kk = (tid >> 4) + rep * 16;
            int c4 = (tid & 15) * 4;
            float4 v = *reinterpret_cast<const float4*>(Wm + (size_t)(k0 + kk) * DIM + col0 + c4);
            *reinterpret_cast<float4*>(&Bs[kk][c4]) = v;
        }
        __syncthreads();
        #pragma unroll
        for (int kk = 0; kk < 32; ++kk) {
            float4 a = *reinterpret_cast<const float4*>(&As[kk][ty * 4]);
            float4 b = *reinterpret_cast<const float4*>(&Bs[kk][tx * 4]);
            float av[4] = {a.x, a.y, a.z, a.w};
            float bv[4] = {b.x, b.y, b.z, b.w};
            #pragma unroll
            for (int i = 0; i < 4; ++i)
                #pragma unroll
                for (int j = 0; j < 4; ++j)
                    c[i][j] = fmaf(av[i], bv[j], c[i][j]);
        }
        __syncthreads();
    }

    float4 bv = *reinterpret_cast<const float4*>(bias + col0 + tx * 4);
    #pragma unroll
    for (int i = 0; i < 4; ++i) {
        int row = row0 + ty * 4 + i;
        if (row < N_NODES) {
            float4 o = make_float4(c[i][0] + bv.x, c[i][1] + bv.y,
                                   c[i][2] + bv.z, c[i][3] + bv.w);
            *reinterpret_cast<float4*>(out + (size_t)row * DIM + col0 + tx * 4) = o;
        }
    }
}

// ---------------- aggregation: one wave per destination node ----------------
// out[n,:] = sum_{e in CSR row n} w_e * h[src_e,:]  +  dis[n]^2 * h[n,:]
// LAYER==1: relu + exact-JAX dropout (x2 scale).  LAYER==2: relu only.
template <int LAYER>
__global__ __launch_bounds__(256) void aggregate_kernel(const float* __restrict__ h,
                                                        const int* __restrict__ row_ptr,
                                                        const int2* __restrict__ recs,
                                                        const float* __restrict__ dis,
                                                        const unsigned* __restrict__ mask,
                                                        float* __restrict__ out) {
    int wave = threadIdx.x >> 6;
    int lane = threadIdx.x & 63;
    int node = blockIdx.x * 4 + wave;   // grid sized so node < N_NODES exactly

    float dn = dis[node];
    float sw = dn * dn;
    float4 v0 = reinterpret_cast<const float4*>(h + (size_t)node * DIM)[lane];
    float ax = sw * v0.x, ay = sw * v0.y, az = sw * v0.z, aw = sw * v0.w;

    int p = row_ptr[node], e = row_ptr[node + 1];
    for (; p + 3 < e; p += 4) {
        int2 r0 = recs[p];
        int2 r1 = recs[p + 1];
        int2 r2 = recs[p + 2];
        int2 r3 = recs[p + 3];
        float w0 = __int_as_float(r0.y);
        float w1 = __int_as_float(r1.y);
        float w2 = __int_as_float(r2.y);
        float w3 = __int_as_float(r3.y);
        float4 u0 = reinterpret_cast<const float4*>(h + (size_t)r0.x * DIM)[lane];
        float4 u1 = reinterpret_cast<const float4*>(h + (size_t)r1.x * DIM)[lane];
        float4 u2 = reinterpret_cast<const float4*>(h + (size_t)r2.x * DIM)[lane];
        float4 u3 = reinterpret_cast<const float4*>(h + (size_t)r3.x * DIM)[lane];
        ax = fmaf(w0, u0.x, ax); ay = fmaf(w0, u0.y, ay);
        az = fmaf(w0, u0.z, az); aw = fmaf(w0, u0.w, aw);
        ax = fmaf(w1, u1.x, ax); ay = fmaf(w1, u1.y, ay);
        az = fmaf(w1, u1.z, az); aw = fmaf(w1, u1.w, aw);
        ax = fmaf(w2, u2.x, ax); ay = fmaf(w2, u2.y, ay);
        az = fmaf(w2, u2.z, az); aw = fmaf(w2, u2.w, aw);
        ax = fmaf(w3, u3.x, ax); ay = fmaf(w3, u3.y, ay);
        az = fmaf(w3, u3.z, az); aw = fmaf(w3, u3.w, aw);
    }
    for (; p < e; ++p) {
        int2 r0 = recs[p];
        float w0 = __int_as_float(r0.y);
        float4 u = reinterpret_cast<const float4*>(h + (size_t)r0.x * DIM)[lane];
        ax = fmaf(w0, u.x, ax); ay = fmaf(w0, u.y, ay);
        az = fmaf(w0, u.z, az); aw = fmaf(w0, u.w, aw);
    }

    ax = fmaxf(ax, 0.f); ay = fmaxf(ay, 0.f);
    az = fmaxf(az, 0.f); aw = fmaxf(aw, 0.f);

    if (LAYER == 1) {
        // element index = node*256 + lane*4 + q ; 8 mask words per node
        unsigned w = mask[node * 8 + (lane >> 3)];
        int b = (lane & 7) * 4;
        ax = ((w >> (b + 0)) & 1u) ? ax * 2.0f : 0.0f;
        ay = ((w >> (b + 1)) & 1u) ? ay * 2.0f : 0.0f;
        az = ((w >> (b + 2)) & 1u) ? az * 2.0f : 0.0f;
        aw = ((w >> (b + 3)) & 1u) ? aw * 2.0f : 0.0f;
    }

    reinterpret_cast<float4*>(out + (size_t)node * DIM)[lane] =
        make_float4(ax, ay, az, aw);
}

// ---------------- mean pooling over sorted batch segments ----------------
__global__ __launch_bounds__(64) void pool_kernel(const float* __restrict__ h,
                                                  const int* __restrict__ gptr,
                                                  float* __restrict__ out) {
    int g = blockIdx.x >> 2;
    int c = blockIdx.x & 3;
    int lane = threadIdx.x;
    int col = c * 64 + lane;
    int s = gptr[g], e = gptr[g + 1];
    float a0 = 0.f, a1 = 0.f, a2 = 0.f, a3 = 0.f;
    int n = s;
    for (; n + 3 < e; n += 4) {
        a0 += h[(size_t)n * DIM + col];
        a1 += h[(size_t)(n + 1) * DIM + col];
        a2 += h[(size_t)(n + 2) * DIM + col];
        a3 += h[(size_t)(n + 3) * DIM + col];
    }
    for (; n < e; ++n) a0 += h[(size_t)n * DIM + col];
    float sum = (a0 + a1) + (a2 + a3);
    out[g * DIM + col] = sum / fmaxf((float)(e - s), 1.0f);
}

// ---------------- launch ----------------
extern "C" void kernel_launch(void* const* d_in, const int* in_sizes, int n_in,
                              void* d_out, int out_size, void* d_ws, size_t ws_size,
                              hipStream_t stream) {
    const float* x     = (const float*)d_in[0];
    const int*   ei    = (const int*)d_in[1];       // [2][N_EDGES] (int32 or int64)
    const int*   batch = (const int*)d_in[2];
    const float* W1    = (const float*)d_in[3];
    const float* b1    = (const float*)d_in[4];
    const float* W2    = (const float*)d_in[5];
    const float* b2    = (const float*)d_in[6];
    float*       out   = (float*)d_out;

    // workspace carve-up (256B aligned)
    char* Wp = (char*)d_ws;
    size_t off = 0;
    auto take = [&](size_t bytes) -> char* {
        char* p = Wp + off;
        off += (bytes + 255) & ~(size_t)255;
        return p;
    };
    int*      cnt    = (int*)take((size_t)N_NODES * 4);
    int*      cur    = (int*)take((size_t)N_NODES * 4);
    int*      rowptr = (int*)take((size_t)(N_NODES + 1) * 4);
    float*    dis    = (float*)take((size_t)N_NODES * 4);
    int2*     recs   = (int2*)take((size_t)N_EDGES * 8);
    int*      gptr   = (int*)take((size_t)(N_GRAPHS + 1) * 4);
    unsigned* mask   = (unsigned*)take((size_t)MASK_WORDS * 4);
    int*      flags  = (int*)take(256);
    float*    bufA   = (float*)take((size_t)N_NODES * DIM * 4);
    float*    bufB   = (float*)take((size_t)N_NODES * DIM * 4);
    (void)ws_size; (void)in_sizes; (void)n_in; (void)out_size;

    // zero the two atomic-counter arrays (cnt, cur are adjacent)
    hipMemsetAsync(cnt, 0, (size_t)((char*)rowptr - (char*)cnt), stream);

    // independent: dropout mask (partitionable threefry)
    mask_kernel<<<(MASK_WORDS + 255) / 256, 256, 0, stream>>>(mask);

    // input dtype-delivery detection, then graph structure
    detect_kernel<<<1, 64, 0, stream>>>(ei, batch, flags);
    edge_count_kernel<<<N_EDGES / 256, 256, 0, stream>>>(ei, flags, cnt);
    scan_nodes_kernel<<<1, 256, 0, stream>>>(cnt, rowptr, dis);
    csr_fill_kernel<<<N_EDGES / 256, 256, 0, stream>>>(ei, flags, rowptr, cur, dis, recs);
    graph_ptr_kernel<<<1, 512, 0, stream>>>(batch, flags, gptr);

    dim3 gemm_grid((N_NODES + 63) / 64, DIM / 64);

    // layer 1
    lin_kernel<<<gemm_grid, 256, 0, stream>>>(x, W1, b1, bufA);
    aggregate_kernel<1><<<N_NODES / 4, 256, 0, stream>>>(bufA, rowptr, recs, dis, mask, bufB);

    // layer 2
    lin_kernel<<<gemm_grid, 256, 0, stream>>>(bufB, W2, b2, bufA);
    aggregate_kernel<2><<<N_NODES / 4, 256, 0, stream>>>(bufA, rowptr, recs, dis, mask, bufB);

    // pooling
    pool_kernel<<<N_GRAPHS * 4, 64, 0, stream>>>(bufB, gptr, out);
}

// Round 6
// 673.618 us; speedup vs baseline: 1.1392x; 1.1392x over previous
//
#include <hip/hip_runtime.h>
#include <cstdint>

// ---------------- problem constants (fixed by the reference) ----------------
#define N_NODES   50000
#define N_EDGES   800000
#define N_GRAPHS  256
#define DIM       256
#define MASK_WORDS 400000           // (N_NODES*DIM)/32 packed keep-bits
#define SCAN_BLOCKS 196             // ceil(N_NODES/256)

// ---------------- threefry2x32, key = (0, 42)  (jax.random.key(42)) --------
__device__ __forceinline__ uint32_t rotl32(uint32_t x, int n) {
    return (x << n) | (x >> (32 - n));
}

__device__ __forceinline__ void threefry2x32_k42(uint32_t& x0, uint32_t& x1) {
    const uint32_t ks0 = 0u, ks1 = 42u, ks2 = 0x1BD11BDAu ^ 0u ^ 42u;
    x0 += ks0; x1 += ks1;
#define TF_R(r) { x0 += x1; x1 = rotl32(x1, (r)); x1 ^= x0; }
    TF_R(13) TF_R(15) TF_R(26) TF_R(6)   x0 += ks1; x1 += ks2 + 1u;
    TF_R(17) TF_R(29) TF_R(16) TF_R(24)  x0 += ks2; x1 += ks0 + 2u;
    TF_R(13) TF_R(15) TF_R(26) TF_R(6)   x0 += ks0; x1 += ks1 + 3u;
    TF_R(17) TF_R(29) TF_R(16) TF_R(24)  x0 += ks1; x1 += ks2 + 4u;
    TF_R(13) TF_R(15) TF_R(26) TF_R(6)   x0 += ks2; x1 += ks0 + 5u;
#undef TF_R
}

// Packed dropout keep-mask — PARTITIONABLE threefry (modern JAX default):
// for element i: (o0,o1) = threefry2x32(key, hi32(i)=0, lo32(i)=i),
// draw = o0 ^ o1, keep <=> MSB(draw)==0.   (verified: round-4 PASS)
__global__ __launch_bounds__(256) void mask_kernel(unsigned* __restrict__ mask) {
    int t = blockIdx.x * 256 + threadIdx.x;
    if (t >= MASK_WORDS) return;
    unsigned m = 0u;
    uint32_t base = (uint32_t)t * 32u;
    #pragma unroll 4
    for (int s = 0; s < 32; ++s) {
        uint32_t x0 = 0u;                 // hi half of 64-bit counter
        uint32_t x1 = base + (uint32_t)s; // lo half = element index
        threefry2x32_k42(x0, x1);
        uint32_t draw = x0 ^ x1;          // xor-fold (partitionable path)
        m |= ((draw >> 31) ^ 1u) << s;
    }
    mask[t] = m;
}

// ---------------- int64-vs-int32 delivery auto-detection ----------------
__global__ void detect_kernel(const int* __restrict__ ei,
                              const int* __restrict__ batch,
                              int* __restrict__ flags) {
    if (threadIdx.x != 0 || blockIdx.x != 0) return;
    int z = 0;
    #pragma unroll
    for (int k = 1; k < 33; k += 2) z |= ei[k];       // int32: random src values
    flags[0] = (z == 0) ? 1 : 0;
    int z2 = batch[25001] | batch[30003] | batch[40005] | batch[49999];
    flags[1] = (z2 == 0) ? 1 : 0;                     // int32: mid/late graph ids
}

// ---------------- degree histogram ----------------
__global__ __launch_bounds__(256) void edge_count_kernel(const int* __restrict__ ei,
                                                         const int* __restrict__ flags,
                                                         int* __restrict__ cnt) {
    int e = blockIdx.x * 256 + threadIdx.x;   // grid sized exactly N_EDGES
    int d = flags[0] ? ei[2 * (N_EDGES + e)] : ei[N_EDGES + e];
    atomicAdd(&cnt[d], 1);
}

// ---------------- hierarchical scan (3 kernels, replaces 137us 1-block scan)
// k1: per-block sums of cnt (coalesced)
__global__ __launch_bounds__(256) void block_sum_kernel(const int* __restrict__ cnt,
                                                        int* __restrict__ bsum) {
    int idx = blockIdx.x * 256 + threadIdx.x;
    int v = (idx < N_NODES) ? cnt[idx] : 0;
    #pragma unroll
    for (int o = 32; o > 0; o >>= 1) v += __shfl_down(v, o, 64);
    __shared__ int s[4];
    if ((threadIdx.x & 63) == 0) s[threadIdx.x >> 6] = v;
    __syncthreads();
    if (threadIdx.x == 0) bsum[blockIdx.x] = s[0] + s[1] + s[2] + s[3];
}

// k2: exclusive scan of the 196 block sums (one block, Hillis-Steele in LDS)
__global__ __launch_bounds__(256) void scan_bsum_kernel(const int* __restrict__ bsum,
                                                        int* __restrict__ boff) {
    __shared__ int s[256];
    int t = threadIdx.x;
    int v = (t < SCAN_BLOCKS) ? bsum[t] : 0;
    s[t] = v;
    __syncthreads();
    #pragma unroll
    for (int o = 1; o < 256; o <<= 1) {
        int u = (t >= o) ? s[t - o] : 0;
        __syncthreads();
        s[t] += u;
        __syncthreads();
    }
    if (t < SCAN_BLOCKS) boff[t] = s[t] - v;   // exclusive
}

// k3: in-block exclusive scan + block offset -> row_ptr; also dis = 1/sqrt(deg+1)
__global__ __launch_bounds__(256) void scan_fill_kernel(const int* __restrict__ cnt,
                                                        const int* __restrict__ boff,
                                                        int* __restrict__ row_ptr,
                                                        float* __restrict__ dis) {
    __shared__ int s[256];
    int t = threadIdx.x;
    int idx = blockIdx.x * 256 + t;
    int v = (idx < N_NODES) ? cnt[idx] : 0;
    s[t] = v;
    __syncthreads();
    #pragma unroll
    for (int o = 1; o < 256; o <<= 1) {
        int u = (t >= o) ? s[t - o] : 0;
        __syncthreads();
        s[t] += u;
        __syncthreads();
    }
    int excl = boff[blockIdx.x] + s[t] - v;
    if (idx < N_NODES) {
        row_ptr[idx] = excl;
        dis[idx] = 1.0f / sqrtf((float)v + 1.0f);   // same numerics as before
        if (idx == N_NODES - 1) row_ptr[N_NODES] = excl + v;
    }
}

// ---------------- CSR fill: (src, norm) records grouped by dst ----------------
__global__ __launch_bounds__(256) void csr_fill_kernel(const int* __restrict__ ei,
                                                       const int* __restrict__ flags,
                                                       const int* __restrict__ row_ptr,
                                                       int* __restrict__ cur,
                                                       const float* __restrict__ dis,
                                                       int2* __restrict__ recs) {
    int e = blockIdx.x * 256 + threadIdx.x;   // grid sized exactly N_EDGES
    int f = flags[0];
    int s = f ? ei[2 * e] : ei[e];
    int d = f ? ei[2 * (N_EDGES + e)] : ei[N_EDGES + e];
    int pos = row_ptr[d] + atomicAdd(&cur[d], 1);
    float w = dis[s] * dis[d];
    recs[pos] = make_int2(s, __float_as_int(w));
}

// ---------------- graph_ptr via binary search on sorted batch ----------------
__global__ __launch_bounds__(512) void graph_ptr_kernel(const int* __restrict__ batch,
                                                        const int* __restrict__ flags,
                                                        int* __restrict__ gptr) {
    int t = threadIdx.x;
    if (t > N_GRAPHS) return;
    int f = flags[1];
    int lo = 0, hi = N_NODES;          // first index with batch[idx] >= t
    while (lo < hi) {
        int mid = (lo + hi) >> 1;
        int v = f ? batch[2 * mid] : batch[mid];
        if (v < t) lo = mid + 1; else hi = mid;
    }
    gptr[t] = lo;
}

// ---------------- f32 tiled GEMM: out[n][j] = sum_k A[n][k]*Wm[k][j] + b[j] --
// 128x128 tile, BK=32, 256 threads, 8x8 per thread (2x arithmetic intensity
// vs the 64x64/4x4 version: 64 FMA per 4 ds_read_b128).
// Accumulation order per output element unchanged (k ascending) -> same absmax.
__global__ __launch_bounds__(256) void lin_kernel(const float* __restrict__ A,
                                                  const float* __restrict__ Wm,
                                                  const float* __restrict__ bias,
                                                  float* __restrict__ out) {
    __shared__ float As[32][132];   // transposed: As[k][m], +4 pad
    __shared__ float Bs[32][132];   // Bs[k][n]
    int tid = threadIdx.x;
    int row0 = blockIdx.x * 128;
    int col0 = blockIdx.y * 128;
    int tx = tid & 15, ty = tid >> 4;
    float c[8][8] = {};

    for (int k0 = 0; k0 < DIM; k0 += 32) {
        // A-tile: 128 rows x 32 k. 256 thr x 4 float4.
        #pragma unroll
        for (int rep = 0; rep < 4; ++rep) {
            int r = (tid >> 3) + rep * 32;
            int c4 = (tid & 7) * 4;
            int grow = row0 + r;
            float4 v = (grow < N_NODES)
                ? *reinterpret_cast<const float4*>(A + (size_t)grow * DIM + k0 + c4)
                : make_float4(0.f, 0.f, 0.f, 0.f);
            As[c4 + 0][r] = v.x; As[c4 + 1][r] = v.y;
            As[c4 + 2][r] = v.z; As[c4 + 3][r] = v.w;
        }
        // B-tile: 32 k x 128 cols. 256 thr x 4 float4 (row-major, b128 writes).
        #pragma unroll
        for (int rep = 0; rep < 4; ++rep) {
            int kk = (tid >> 5) + rep * 8;
            int c4 = (tid & 31) * 4;
            float4 v = *reinterpret_cast<const float4*>(Wm + (size_t)(k0 + kk) * DIM + col0 + c4);
            *reinterpret_cast<float4*>(&Bs[kk][c4]) = v;
        }
        __syncthreads();
        #pragma unroll
        for (int kk = 0; kk < 32; ++kk) {
            float4 a0 = *reinterpret_cast<const float4*>(&As[kk][ty * 8]);
            float4 a1 = *reinterpret_cast<const float4*>(&As[kk][ty * 8 + 4]);
            float4 b0 = *reinterpret_cast<const float4*>(&Bs[kk][tx * 8]);
            float4 b1 = *reinterpret_cast<const float4*>(&Bs[kk][tx * 8 + 4]);
            float av[8] = {a0.x, a0.y, a0.z, a0.w, a1.x, a1.y, a1.z, a1.w};
            float bv[8] = {b0.x, b0.y, b0.z, b0.w, b1.x, b1.y, b1.z, b1.w};
            #pragma unroll
            for (int i = 0; i < 8; ++i)
                #pragma unroll
                for (int j = 0; j < 8; ++j)
                    c[i][j] = fmaf(av[i], bv[j], c[i][j]);
        }
        __syncthreads();
    }

    float4 bv0 = *reinterpret_cast<const float4*>(bias + col0 + tx * 8);
    float4 bv1 = *reinterpret_cast<const float4*>(bias + col0 + tx * 8 + 4);
    #pragma unroll
    for (int i = 0; i < 8; ++i) {
        int row = row0 + ty * 8 + i;
        if (row < N_NODES) {
            float4 o0 = make_float4(c[i][0] + bv0.x, c[i][1] + bv0.y,
                                    c[i][2] + bv0.z, c[i][3] + bv0.w);
            float4 o1 = make_float4(c[i][4] + bv1.x, c[i][5] + bv1.y,
                                    c[i][6] + bv1.z, c[i][7] + bv1.w);
            *reinterpret_cast<float4*>(out + (size_t)row * DIM + col0 + tx * 8) = o0;
            *reinterpret_cast<float4*>(out + (size_t)row * DIM + col0 + tx * 8 + 4) = o1;
        }
    }
}

// ---------------- aggregation: one wave per destination node ----------------
// out[n,:] = sum_{e in CSR row n} w_e * h[src_e,:]  +  dis[n]^2 * h[n,:]
// LAYER==1: relu + exact-JAX dropout (x2 scale).  LAYER==2: relu only.
template <int LAYER>
__global__ __launch_bounds__(256) void aggregate_kernel(const float* __restrict__ h,
                                                        const int* __restrict__ row_ptr,
                                                        const int2* __restrict__ recs,
                                                        const float* __restrict__ dis,
                                                        const unsigned* __restrict__ mask,
                                                        float* __restrict__ out) {
    int wave = threadIdx.x >> 6;
    int lane = threadIdx.x & 63;
    int node = blockIdx.x * 4 + wave;   // grid sized so node < N_NODES exactly

    float dn = dis[node];
    float sw = dn * dn;
    float4 v0 = reinterpret_cast<const float4*>(h + (size_t)node * DIM)[lane];
    float ax = sw * v0.x, ay = sw * v0.y, az = sw * v0.z, aw = sw * v0.w;

    int p = row_ptr[node], e = row_ptr[node + 1];
    for (; p + 3 < e; p += 4) {
        int2 r0 = recs[p];
        int2 r1 = recs[p + 1];
        int2 r2 = recs[p + 2];
        int2 r3 = recs[p + 3];
        float w0 = __int_as_float(r0.y);
        float w1 = __int_as_float(r1.y);
        float w2 = __int_as_float(r2.y);
        float w3 = __int_as_float(r3.y);
        float4 u0 = reinterpret_cast<const float4*>(h + (size_t)r0.x * DIM)[lane];
        float4 u1 = reinterpret_cast<const float4*>(h + (size_t)r1.x * DIM)[lane];
        float4 u2 = reinterpret_cast<const float4*>(h + (size_t)r2.x * DIM)[lane];
        float4 u3 = reinterpret_cast<const float4*>(h + (size_t)r3.x * DIM)[lane];
        ax = fmaf(w0, u0.x, ax); ay = fmaf(w0, u0.y, ay);
        az = fmaf(w0, u0.z, az); aw = fmaf(w0, u0.w, aw);
        ax = fmaf(w1, u1.x, ax); ay = fmaf(w1, u1.y, ay);
        az = fmaf(w1, u1.z, az); aw = fmaf(w1, u1.w, aw);
        ax = fmaf(w2, u2.x, ax); ay = fmaf(w2, u2.y, ay);
        az = fmaf(w2, u2.z, az); aw = fmaf(w2, u2.w, aw);
        ax = fmaf(w3, u3.x, ax); ay = fmaf(w3, u3.y, ay);
        az = fmaf(w3, u3.z, az); aw = fmaf(w3, u3.w, aw);
    }
    for (; p < e; ++p) {
        int2 r0 = recs[p];
        float w0 = __int_as_float(r0.y);
        float4 u = reinterpret_cast<const float4*>(h + (size_t)r0.x * DIM)[lane];
        ax = fmaf(w0, u.x, ax); ay = fmaf(w0, u.y, ay);
        az = fmaf(w0, u.z, az); aw = fmaf(w0, u.w, aw);
    }

    ax = fmaxf(ax, 0.f); ay = fmaxf(ay, 0.f);
    az = fmaxf(az, 0.f); aw = fmaxf(aw, 0.f);

    if (LAYER == 1) {
        // element index = node*256 + lane*4 + q ; 8 mask words per node
        unsigned w = mask[node * 8 + (lane >> 3)];
        int b = (lane & 7) * 4;
        ax = ((w >> (b + 0)) & 1u) ? ax * 2.0f : 0.0f;
        ay = ((w >> (b + 1)) & 1u) ? ay * 2.0f : 0.0f;
        az = ((w >> (b + 2)) & 1u) ? az * 2.0f : 0.0f;
        aw = ((w >> (b + 3)) & 1u) ? aw * 2.0f : 0.0f;
    }

    reinterpret_cast<float4*>(out + (size_t)node * DIM)[lane] =
        make_float4(ax, ay, az, aw);
}

// ---------------- mean pooling over sorted batch segments ----------------
__global__ __launch_bounds__(64) void pool_kernel(const float* __restrict__ h,
                                                  const int* __restrict__ gptr,
                                                  float* __restrict__ out) {
    int g = blockIdx.x >> 2;
    int c = blockIdx.x & 3;
    int lane = threadIdx.x;
    int col = c * 64 + lane;
    int s = gptr[g], e = gptr[g + 1];
    float a0 = 0.f, a1 = 0.f, a2 = 0.f, a3 = 0.f;
    int n = s;
    for (; n + 3 < e; n += 4) {
        a0 += h[(size_t)n * DIM + col];
        a1 += h[(size_t)(n + 1) * DIM + col];
        a2 += h[(size_t)(n + 2) * DIM + col];
        a3 += h[(size_t)(n + 3) * DIM + col];
    }
    for (; n < e; ++n) a0 += h[(size_t)n * DIM + col];
    float sum = (a0 + a1) + (a2 + a3);
    out[g * DIM + col] = sum / fmaxf((float)(e - s), 1.0f);
}

// ---------------- launch ----------------
extern "C" void kernel_launch(void* const* d_in, const int* in_sizes, int n_in,
                              void* d_out, int out_size, void* d_ws, size_t ws_size,
                              hipStream_t stream) {
    const float* x     = (const float*)d_in[0];
    const int*   ei    = (const int*)d_in[1];       // [2][N_EDGES] (int32 or int64)
    const int*   batch = (const int*)d_in[2];
    const float* W1    = (const float*)d_in[3];
    const float* b1    = (const float*)d_in[4];
    const float* W2    = (const float*)d_in[5];
    const float* b2    = (const float*)d_in[6];
    float*       out   = (float*)d_out;

    // workspace carve-up (256B aligned)
    char* Wp = (char*)d_ws;
    size_t off = 0;
    auto take = [&](size_t bytes) -> char* {
        char* p = Wp + off;
        off += (bytes + 255) & ~(size_t)255;
        return p;
    };
    int*      cnt    = (int*)take((size_t)N_NODES * 4);
    int*      cur    = (int*)take((size_t)N_NODES * 4);
    int*      rowptr = (int*)take((size_t)(N_NODES + 1) * 4);
    float*    dis    = (float*)take((size_t)N_NODES * 4);
    int2*     recs   = (int2*)take((size_t)N_EDGES * 8);
    int*      gptr   = (int*)take((size_t)(N_GRAPHS + 1) * 4);
    unsigned* mask   = (unsigned*)take((size_t)MASK_WORDS * 4);
    int*      flags  = (int*)take(256);
    int*      bsum   = (int*)take((size_t)SCAN_BLOCKS * 4);
    int*      boff   = (int*)take((size_t)(SCAN_BLOCKS + 1) * 4);
    float*    bufA   = (float*)take((size_t)N_NODES * DIM * 4);
    float*    bufB   = (float*)take((size_t)N_NODES * DIM * 4);
    (void)ws_size; (void)in_sizes; (void)n_in; (void)out_size;

    // zero the two atomic-counter arrays (cnt, cur are adjacent)
    hipMemsetAsync(cnt, 0, (size_t)((char*)rowptr - (char*)cnt), stream);

    // independent: dropout mask (partitionable threefry)
    mask_kernel<<<(MASK_WORDS + 255) / 256, 256, 0, stream>>>(mask);

    // input dtype-delivery detection, then graph structure
    detect_kernel<<<1, 64, 0, stream>>>(ei, batch, flags);
    edge_count_kernel<<<N_EDGES / 256, 256, 0, stream>>>(ei, flags, cnt);
    block_sum_kernel<<<SCAN_BLOCKS, 256, 0, stream>>>(cnt, bsum);
    scan_bsum_kernel<<<1, 256, 0, stream>>>(bsum, boff);
    scan_fill_kernel<<<SCAN_BLOCKS, 256, 0, stream>>>(cnt, boff, rowptr, dis);
    csr_fill_kernel<<<N_EDGES / 256, 256, 0, stream>>>(ei, flags, rowptr, cur, dis, recs);
    graph_ptr_kernel<<<1, 512, 0, stream>>>(batch, flags, gptr);

    dim3 gemm_grid((N_NODES + 127) / 128, DIM / 128);

    // layer 1
    lin_kernel<<<gemm_grid, 256, 0, stream>>>(x, W1, b1, bufA);
    aggregate_kernel<1><<<N_NODES / 4, 256, 0, stream>>>(bufA, rowptr, recs, dis, mask, bufB);

    // layer 2
    lin_kernel<<<gemm_grid, 256, 0, stream>>>(bufB, W2, b2, bufA);
    aggregate_kernel<2><<<N_NODES / 4, 256, 0, stream>>>(bufA, rowptr, recs, dis, mask, bufB);

    // pooling
    pool_kernel<<<N_GRAPHS * 4, 64, 0, stream>>>(bufB, gptr, out);
}

// Round 7
// 574.390 us; speedup vs baseline: 1.3360x; 1.1728x over previous
//
#include <hip/hip_runtime.h>
#include <cstdint>

// ---------------- problem constants (fixed by the reference) ----------------
#define N_NODES   50000
#define N_EDGES   800000
#define N_GRAPHS  256
#define DIM       256
#define MASK_WORDS 400000           // (N_NODES*DIM)/32 packed keep-bits
#define SCAN_BLOCKS 196             // ceil(N_NODES/256)

// ---------------- threefry2x32, key = (0, 42)  (jax.random.key(42)) --------
__device__ __forceinline__ uint32_t rotl32(uint32_t x, int n) {
    return (x << n) | (x >> (32 - n));
}

__device__ __forceinline__ void threefry2x32_k42(uint32_t& x0, uint32_t& x1) {
    const uint32_t ks0 = 0u, ks1 = 42u, ks2 = 0x1BD11BDAu ^ 0u ^ 42u;
    x0 += ks0; x1 += ks1;
#define TF_R(r) { x0 += x1; x1 = rotl32(x1, (r)); x1 ^= x0; }
    TF_R(13) TF_R(15) TF_R(26) TF_R(6)   x0 += ks1; x1 += ks2 + 1u;
    TF_R(17) TF_R(29) TF_R(16) TF_R(24)  x0 += ks2; x1 += ks0 + 2u;
    TF_R(13) TF_R(15) TF_R(26) TF_R(6)   x0 += ks0; x1 += ks1 + 3u;
    TF_R(17) TF_R(29) TF_R(16) TF_R(24)  x0 += ks1; x1 += ks2 + 4u;
    TF_R(13) TF_R(15) TF_R(26) TF_R(6)   x0 += ks2; x1 += ks0 + 5u;
#undef TF_R
}

// bf16 helpers: RNE pack (min quantization error), cheap unpack
__device__ __forceinline__ uint32_t bf16_rne(float f) {
    uint32_t u = __float_as_uint(f);
    return (u + 0x7FFFu + ((u >> 16) & 1u)) >> 16;
}
__device__ __forceinline__ uint32_t bf16_pack2(float a, float b) {
    return bf16_rne(a) | (bf16_rne(b) << 16);
}
__device__ __forceinline__ float bf16_lo(uint32_t u) { return __uint_as_float(u << 16); }
__device__ __forceinline__ float bf16_hi(uint32_t u) { return __uint_as_float(u & 0xFFFF0000u); }

// Packed dropout keep-mask — PARTITIONABLE threefry (modern JAX default):
// for element i: (o0,o1) = threefry2x32(key, hi32(i)=0, lo32(i)=i),
// draw = o0 ^ o1, keep <=> MSB(draw)==0.   (verified: round-4 PASS)
__global__ __launch_bounds__(256) void mask_kernel(unsigned* __restrict__ mask) {
    int t = blockIdx.x * 256 + threadIdx.x;
    if (t >= MASK_WORDS) return;
    unsigned m = 0u;
    uint32_t base = (uint32_t)t * 32u;
    #pragma unroll 4
    for (int s = 0; s < 32; ++s) {
        uint32_t x0 = 0u;                 // hi half of 64-bit counter
        uint32_t x1 = base + (uint32_t)s; // lo half = element index
        threefry2x32_k42(x0, x1);
        uint32_t draw = x0 ^ x1;          // xor-fold (partitionable path)
        m |= ((draw >> 31) ^ 1u) << s;
    }
    mask[t] = m;
}

// ---------------- int64-vs-int32 delivery auto-detection ----------------
__global__ void detect_kernel(const int* __restrict__ ei,
                              const int* __restrict__ batch,
                              int* __restrict__ flags) {
    if (threadIdx.x != 0 || blockIdx.x != 0) return;
    int z = 0;
    #pragma unroll
    for (int k = 1; k < 33; k += 2) z |= ei[k];       // int32: random src values
    flags[0] = (z == 0) ? 1 : 0;
    int z2 = batch[25001] | batch[30003] | batch[40005] | batch[49999];
    flags[1] = (z2 == 0) ? 1 : 0;                     // int32: mid/late graph ids
}

// ---------------- degree histogram ----------------
__global__ __launch_bounds__(256) void edge_count_kernel(const int* __restrict__ ei,
                                                         const int* __restrict__ flags,
                                                         int* __restrict__ cnt) {
    int e = blockIdx.x * 256 + threadIdx.x;   // grid sized exactly N_EDGES
    int d = flags[0] ? ei[2 * (N_EDGES + e)] : ei[N_EDGES + e];
    atomicAdd(&cnt[d], 1);
}

// ---------------- hierarchical scan ----------------
__global__ __launch_bounds__(256) void block_sum_kernel(const int* __restrict__ cnt,
                                                        int* __restrict__ bsum) {
    int idx = blockIdx.x * 256 + threadIdx.x;
    int v = (idx < N_NODES) ? cnt[idx] : 0;
    #pragma unroll
    for (int o = 32; o > 0; o >>= 1) v += __shfl_down(v, o, 64);
    __shared__ int s[4];
    if ((threadIdx.x & 63) == 0) s[threadIdx.x >> 6] = v;
    __syncthreads();
    if (threadIdx.x == 0) bsum[blockIdx.x] = s[0] + s[1] + s[2] + s[3];
}

__global__ __launch_bounds__(256) void scan_bsum_kernel(const int* __restrict__ bsum,
                                                        int* __restrict__ boff) {
    __shared__ int s[256];
    int t = threadIdx.x;
    int v = (t < SCAN_BLOCKS) ? bsum[t] : 0;
    s[t] = v;
    __syncthreads();
    #pragma unroll
    for (int o = 1; o < 256; o <<= 1) {
        int u = (t >= o) ? s[t - o] : 0;
        __syncthreads();
        s[t] += u;
        __syncthreads();
    }
    if (t < SCAN_BLOCKS) boff[t] = s[t] - v;   // exclusive
}

__global__ __launch_bounds__(256) void scan_fill_kernel(const int* __restrict__ cnt,
                                                        const int* __restrict__ boff,
                                                        int* __restrict__ row_ptr,
                                                        float* __restrict__ dis) {
    __shared__ int s[256];
    int t = threadIdx.x;
    int idx = blockIdx.x * 256 + t;
    int v = (idx < N_NODES) ? cnt[idx] : 0;
    s[t] = v;
    __syncthreads();
    #pragma unroll
    for (int o = 1; o < 256; o <<= 1) {
        int u = (t >= o) ? s[t - o] : 0;
        __syncthreads();
        s[t] += u;
        __syncthreads();
    }
    int excl = boff[blockIdx.x] + s[t] - v;
    if (idx < N_NODES) {
        row_ptr[idx] = excl;
        dis[idx] = 1.0f / sqrtf((float)v + 1.0f);
        if (idx == N_NODES - 1) row_ptr[N_NODES] = excl + v;
    }
}

// ---------------- CSR fill: (src, norm) records grouped by dst ----------------
__global__ __launch_bounds__(256) void csr_fill_kernel(const int* __restrict__ ei,
                                                       const int* __restrict__ flags,
                                                       const int* __restrict__ row_ptr,
                                                       int* __restrict__ cur,
                                                       const float* __restrict__ dis,
                                                       int2* __restrict__ recs) {
    int e = blockIdx.x * 256 + threadIdx.x;   // grid sized exactly N_EDGES
    int f = flags[0];
    int s = f ? ei[2 * e] : ei[e];
    int d = f ? ei[2 * (N_EDGES + e)] : ei[N_EDGES + e];
    int pos = row_ptr[d] + atomicAdd(&cur[d], 1);
    float w = dis[s] * dis[d];
    recs[pos] = make_int2(s, __float_as_int(w));
}

// ---------------- graph_ptr via binary search on sorted batch ----------------
__global__ __launch_bounds__(512) void graph_ptr_kernel(const int* __restrict__ batch,
                                                        const int* __restrict__ flags,
                                                        int* __restrict__ gptr) {
    int t = threadIdx.x;
    if (t > N_GRAPHS) return;
    int f = flags[1];
    int lo = 0, hi = N_NODES;          // first index with batch[idx] >= t
    while (lo < hi) {
        int mid = (lo + hi) >> 1;
        int v = f ? batch[2 * mid] : batch[mid];
        if (v < t) lo = mid + 1; else hi = mid;
    }
    gptr[t] = lo;
}

// ---------------- f32 tiled GEMM -> bf16 output ----------------
// out_bf[n][j] = bf16_rne( sum_k A[n][k]*Wm[k][j] + b[j] )
// 128x128 tile, BK=32, 256 threads, 8x8 per thread. Output consumed only by
// the gather-aggregation, which is bf16 (halves its fetch traffic).
__global__ __launch_bounds__(256) void lin_kernel(const float* __restrict__ A,
                                                  const float* __restrict__ Wm,
                                                  const float* __restrict__ bias,
                                                  ushort* __restrict__ out_bf) {
    __shared__ float As[32][132];   // transposed: As[k][m], +4 pad
    __shared__ float Bs[32][132];   // Bs[k][n]
    int tid = threadIdx.x;
    int row0 = blockIdx.x * 128;
    int col0 = blockIdx.y * 128;
    int tx = tid & 15, ty = tid >> 4;
    float c[8][8] = {};

    for (int k0 = 0; k0 < DIM; k0 += 32) {
        #pragma unroll
        for (int rep = 0; rep < 4; ++rep) {
            int r = (tid >> 3) + rep * 32;
            int c4 = (tid & 7) * 4;
            int grow = row0 + r;
            float4 v = (grow < N_NODES)
                ? *reinterpret_cast<const float4*>(A + (size_t)grow * DIM + k0 + c4)
                : make_float4(0.f, 0.f, 0.f, 0.f);
            As[c4 + 0][r] = v.x; As[c4 + 1][r] = v.y;
            As[c4 + 2][r] = v.z; As[c4 + 3][r] = v.w;
        }
        #pragma unroll
        for (int rep = 0; rep < 4; ++rep) {
            int kk = (tid >> 5) + rep * 8;
            int c4 = (tid & 31) * 4;
            float4 v = *reinterpret_cast<const float4*>(Wm + (size_t)(k0 + kk) * DIM + col0 + c4);
            *reinterpret_cast<float4*>(&Bs[kk][c4]) = v;
        }
        __syncthreads();
        #pragma unroll
        for (int kk = 0; kk < 32; ++kk) {
            float4 a0 = *reinterpret_cast<const float4*>(&As[kk][ty * 8]);
            float4 a1 = *reinterpret_cast<const float4*>(&As[kk][ty * 8 + 4]);
            float4 b0 = *reinterpret_cast<const float4*>(&Bs[kk][tx * 8]);
            float4 b1 = *reinterpret_cast<const float4*>(&Bs[kk][tx * 8 + 4]);
            float av[8] = {a0.x, a0.y, a0.z, a0.w, a1.x, a1.y, a1.z, a1.w};
            float bv[8] = {b0.x, b0.y, b0.z, b0.w, b1.x, b1.y, b1.z, b1.w};
            #pragma unroll
            for (int i = 0; i < 8; ++i)
                #pragma unroll
                for (int j = 0; j < 8; ++j)
                    c[i][j] = fmaf(av[i], bv[j], c[i][j]);
        }
        __syncthreads();
    }

    float4 bv0 = *reinterpret_cast<const float4*>(bias + col0 + tx * 8);
    float4 bv1 = *reinterpret_cast<const float4*>(bias + col0 + tx * 8 + 4);
    float bb[8] = {bv0.x, bv0.y, bv0.z, bv0.w, bv1.x, bv1.y, bv1.z, bv1.w};
    #pragma unroll
    for (int i = 0; i < 8; ++i) {
        int row = row0 + ty * 8 + i;
        if (row < N_NODES) {
            uint4 o;
            o.x = bf16_pack2(c[i][0] + bb[0], c[i][1] + bb[1]);
            o.y = bf16_pack2(c[i][2] + bb[2], c[i][3] + bb[3]);
            o.z = bf16_pack2(c[i][4] + bb[4], c[i][5] + bb[5]);
            o.w = bf16_pack2(c[i][6] + bb[6], c[i][7] + bb[7]);
            *reinterpret_cast<uint4*>(out_bf + (size_t)row * DIM + col0 + tx * 8) = o;
        }
    }
}

// ---------------- aggregation: one wave per destination node ----------------
// Gathers bf16 rows (512B each, half the fetch traffic of f32), accumulates f32.
// out[n,:] = sum_{e in CSR row n} w_e * h[src_e,:]  +  dis[n]^2 * h[n,:]
// LAYER==1: relu + exact-JAX dropout (x2 scale).  LAYER==2: relu only.
template <int LAYER>
__global__ __launch_bounds__(256) void aggregate_kernel(const ushort* __restrict__ hb,
                                                        const int* __restrict__ row_ptr,
                                                        const int2* __restrict__ recs,
                                                        const float* __restrict__ dis,
                                                        const unsigned* __restrict__ mask,
                                                        float* __restrict__ out) {
    int wave = threadIdx.x >> 6;
    int lane = threadIdx.x & 63;
    int node = blockIdx.x * 4 + wave;   // grid sized so node < N_NODES exactly

    float dn = dis[node];
    float sw = dn * dn;
    uint2 s0 = reinterpret_cast<const uint2*>(hb + (size_t)node * DIM)[lane];
    float ax = sw * bf16_lo(s0.x), ay = sw * bf16_hi(s0.x);
    float az = sw * bf16_lo(s0.y), aw = sw * bf16_hi(s0.y);

    int p = row_ptr[node], e = row_ptr[node + 1];
    for (; p + 3 < e; p += 4) {
        int2 r0 = recs[p];
        int2 r1 = recs[p + 1];
        int2 r2 = recs[p + 2];
        int2 r3 = recs[p + 3];
        float w0 = __int_as_float(r0.y);
        float w1 = __int_as_float(r1.y);
        float w2 = __int_as_float(r2.y);
        float w3 = __int_as_float(r3.y);
        uint2 u0 = reinterpret_cast<const uint2*>(hb + (size_t)r0.x * DIM)[lane];
        uint2 u1 = reinterpret_cast<const uint2*>(hb + (size_t)r1.x * DIM)[lane];
        uint2 u2 = reinterpret_cast<const uint2*>(hb + (size_t)r2.x * DIM)[lane];
        uint2 u3 = reinterpret_cast<const uint2*>(hb + (size_t)r3.x * DIM)[lane];
        ax = fmaf(w0, bf16_lo(u0.x), ax); ay = fmaf(w0, bf16_hi(u0.x), ay);
        az = fmaf(w0, bf16_lo(u0.y), az); aw = fmaf(w0, bf16_hi(u0.y), aw);
        ax = fmaf(w1, bf16_lo(u1.x), ax); ay = fmaf(w1, bf16_hi(u1.x), ay);
        az = fmaf(w1, bf16_lo(u1.y), az); aw = fmaf(w1, bf16_hi(u1.y), aw);
        ax = fmaf(w2, bf16_lo(u2.x), ax); ay = fmaf(w2, bf16_hi(u2.x), ay);
        az = fmaf(w2, bf16_lo(u2.y), az); aw = fmaf(w2, bf16_hi(u2.y), aw);
        ax = fmaf(w3, bf16_lo(u3.x), ax); ay = fmaf(w3, bf16_hi(u3.x), ay);
        az = fmaf(w3, bf16_lo(u3.y), az); aw = fmaf(w3, bf16_hi(u3.y), aw);
    }
    for (; p < e; ++p) {
        int2 r0 = recs[p];
        float w0 = __int_as_float(r0.y);
        uint2 u = reinterpret_cast<const uint2*>(hb + (size_t)r0.x * DIM)[lane];
        ax = fmaf(w0, bf16_lo(u.x), ax); ay = fmaf(w0, bf16_hi(u.x), ay);
        az = fmaf(w0, bf16_lo(u.y), az); aw = fmaf(w0, bf16_hi(u.y), aw);
    }

    ax = fmaxf(ax, 0.f); ay = fmaxf(ay, 0.f);
    az = fmaxf(az, 0.f); aw = fmaxf(aw, 0.f);

    if (LAYER == 1) {
        // element index = node*256 + lane*4 + q ; 8 mask words per node
        unsigned w = mask[node * 8 + (lane >> 3)];
        int b = (lane & 7) * 4;
        ax = ((w >> (b + 0)) & 1u) ? ax * 2.0f : 0.0f;
        ay = ((w >> (b + 1)) & 1u) ? ay * 2.0f : 0.0f;
        az = ((w >> (b + 2)) & 1u) ? az * 2.0f : 0.0f;
        aw = ((w >> (b + 3)) & 1u) ? aw * 2.0f : 0.0f;
    }

    reinterpret_cast<float4*>(out + (size_t)node * DIM)[lane] =
        make_float4(ax, ay, az, aw);
}

// ---------------- mean pooling over sorted batch segments ----------------
__global__ __launch_bounds__(64) void pool_kernel(const float* __restrict__ h,
                                                  const int* __restrict__ gptr,
                                                  float* __restrict__ out) {
    int g = blockIdx.x >> 2;
    int c = blockIdx.x & 3;
    int lane = threadIdx.x;
    int col = c * 64 + lane;
    int s = gptr[g], e = gptr[g + 1];
    float a0 = 0.f, a1 = 0.f, a2 = 0.f, a3 = 0.f;
    int n = s;
    for (; n + 3 < e; n += 4) {
        a0 += h[(size_t)n * DIM + col];
        a1 += h[(size_t)(n + 1) * DIM + col];
        a2 += h[(size_t)(n + 2) * DIM + col];
        a3 += h[(size_t)(n + 3) * DIM + col];
    }
    for (; n < e; ++n) a0 += h[(size_t)n * DIM + col];
    float sum = (a0 + a1) + (a2 + a3);
    out[g * DIM + col] = sum / fmaxf((float)(e - s), 1.0f);
}

// ---------------- launch ----------------
extern "C" void kernel_launch(void* const* d_in, const int* in_sizes, int n_in,
                              void* d_out, int out_size, void* d_ws, size_t ws_size,
                              hipStream_t stream) {
    const float* x     = (const float*)d_in[0];
    const int*   ei    = (const int*)d_in[1];       // [2][N_EDGES] (int32 or int64)
    const int*   batch = (const int*)d_in[2];
    const float* W1    = (const float*)d_in[3];
    const float* b1    = (const float*)d_in[4];
    const float* W2    = (const float*)d_in[5];
    const float* b2    = (const float*)d_in[6];
    float*       out   = (float*)d_out;

    // workspace carve-up (256B aligned)
    char* Wp = (char*)d_ws;
    size_t off = 0;
    auto take = [&](size_t bytes) -> char* {
        char* p = Wp + off;
        off += (bytes + 255) & ~(size_t)255;
        return p;
    };
    int*      cnt    = (int*)take((size_t)N_NODES * 4);
    int*      cur    = (int*)take((size_t)N_NODES * 4);
    int*      rowptr = (int*)take((size_t)(N_NODES + 1) * 4);
    float*    dis    = (float*)take((size_t)N_NODES * 4);
    int2*     recs   = (int2*)take((size_t)N_EDGES * 8);
    int*      gptr   = (int*)take((size_t)(N_GRAPHS + 1) * 4);
    unsigned* mask   = (unsigned*)take((size_t)MASK_WORDS * 4);
    int*      flags  = (int*)take(256);
    int*      bsum   = (int*)take((size_t)SCAN_BLOCKS * 4);
    int*      boff   = (int*)take((size_t)(SCAN_BLOCKS + 1) * 4);
    ushort*   hbf    = (ushort*)take((size_t)N_NODES * DIM * 2);   // bf16 lin out
    float*    bufA   = (float*)take((size_t)N_NODES * DIM * 4);    // agg1 out (f32)
    float*    bufB   = (float*)take((size_t)N_NODES * DIM * 4);    // agg2 out (f32)
    (void)ws_size; (void)in_sizes; (void)n_in; (void)out_size;

    // zero the two atomic-counter arrays (cnt, cur are adjacent)
    hipMemsetAsync(cnt, 0, (size_t)((char*)rowptr - (char*)cnt), stream);

    // independent: dropout mask (partitionable threefry)
    mask_kernel<<<(MASK_WORDS + 255) / 256, 256, 0, stream>>>(mask);

    // input dtype-delivery detection, then graph structure
    detect_kernel<<<1, 64, 0, stream>>>(ei, batch, flags);
    edge_count_kernel<<<N_EDGES / 256, 256, 0, stream>>>(ei, flags, cnt);
    block_sum_kernel<<<SCAN_BLOCKS, 256, 0, stream>>>(cnt, bsum);
    scan_bsum_kernel<<<1, 256, 0, stream>>>(bsum, boff);
    scan_fill_kernel<<<SCAN_BLOCKS, 256, 0, stream>>>(cnt, boff, rowptr, dis);
    csr_fill_kernel<<<N_EDGES / 256, 256, 0, stream>>>(ei, flags, rowptr, cur, dis, recs);
    graph_ptr_kernel<<<1, 512, 0, stream>>>(batch, flags, gptr);

    dim3 gemm_grid((N_NODES + 127) / 128, DIM / 128);

    // layer 1: lin -> bf16, gather-aggregate -> f32
    lin_kernel<<<gemm_grid, 256, 0, stream>>>(x, W1, b1, hbf);
    aggregate_kernel<1><<<N_NODES / 4, 256, 0, stream>>>(hbf, rowptr, recs, dis, mask, bufA);

    // layer 2
    lin_kernel<<<gemm_grid, 256, 0, stream>>>(bufA, W2, b2, hbf);
    aggregate_kernel<2><<<N_NODES / 4, 256, 0, stream>>>(hbf, rowptr, recs, dis, mask, bufB);

    // pooling
    pool_kernel<<<N_GRAPHS * 4, 64, 0, stream>>>(bufB, gptr, out);
}

// Round 10
// 466.292 us; speedup vs baseline: 1.6457x; 1.2318x over previous
//
#include <hip/hip_runtime.h>
#include <cstdint>

// ---------------- problem constants (fixed by the reference) ----------------
#define N_NODES   50000
#define N_EDGES   800000
#define N_GRAPHS  256
#define DIM       256
#define MASK_WORDS 400000           // (N_NODES*DIM)/32 packed keep-bits
#define SCAN_BLOCKS 196             // ceil(N_NODES/256)

typedef __attribute__((ext_vector_type(8))) short bf16x8;
typedef __attribute__((ext_vector_type(4))) float f32x4;

// ---------------- threefry2x32, key = (0, 42)  (jax.random.key(42)) --------
__device__ __forceinline__ uint32_t rotl32(uint32_t x, int n) {
    return (x << n) | (x >> (32 - n));
}

__device__ __forceinline__ void threefry2x32_k42(uint32_t& x0, uint32_t& x1) {
    const uint32_t ks0 = 0u, ks1 = 42u, ks2 = 0x1BD11BDAu ^ 0u ^ 42u;
    x0 += ks0; x1 += ks1;
#define TF_R(r) { x0 += x1; x1 = rotl32(x1, (r)); x1 ^= x0; }
    TF_R(13) TF_R(15) TF_R(26) TF_R(6)   x0 += ks1; x1 += ks2 + 1u;
    TF_R(17) TF_R(29) TF_R(16) TF_R(24)  x0 += ks2; x1 += ks0 + 2u;
    TF_R(13) TF_R(15) TF_R(26) TF_R(6)   x0 += ks0; x1 += ks1 + 3u;
    TF_R(17) TF_R(29) TF_R(16) TF_R(24)  x0 += ks1; x1 += ks2 + 4u;
    TF_R(13) TF_R(15) TF_R(26) TF_R(6)   x0 += ks2; x1 += ks0 + 5u;
#undef TF_R
}

// bf16 helpers: RNE pack (min quantization error), cheap unpack
__device__ __forceinline__ uint32_t bf16_rne(float f) {
    uint32_t u = __float_as_uint(f);
    return (u + 0x7FFFu + ((u >> 16) & 1u)) >> 16;
}
__device__ __forceinline__ uint32_t bf16_pack2(float a, float b) {
    return bf16_rne(a) | (bf16_rne(b) << 16);
}
__device__ __forceinline__ float bf16_lo(uint32_t u) { return __uint_as_float(u << 16); }
__device__ __forceinline__ float bf16_hi(uint32_t u) { return __uint_as_float(u & 0xFFFF0000u); }

// Packed dropout keep-mask — PARTITIONABLE threefry (verified round-4 PASS)
__global__ __launch_bounds__(256) void mask_kernel(unsigned* __restrict__ mask) {
    int t = blockIdx.x * 256 + threadIdx.x;
    if (t >= MASK_WORDS) return;
    unsigned m = 0u;
    uint32_t base = (uint32_t)t * 32u;
    #pragma unroll 4
    for (int s = 0; s < 32; ++s) {
        uint32_t x0 = 0u;
        uint32_t x1 = base + (uint32_t)s;
        threefry2x32_k42(x0, x1);
        uint32_t draw = x0 ^ x1;
        m |= ((draw >> 31) ^ 1u) << s;
    }
    mask[t] = m;
}

// ---------------- int64-vs-int32 delivery auto-detection ----------------
__global__ void detect_kernel(const int* __restrict__ ei,
                              const int* __restrict__ batch,
                              int* __restrict__ flags) {
    if (threadIdx.x != 0 || blockIdx.x != 0) return;
    int z = 0;
    #pragma unroll
    for (int k = 1; k < 33; k += 2) z |= ei[k];
    flags[0] = (z == 0) ? 1 : 0;
    int z2 = batch[25001] | batch[30003] | batch[40005] | batch[49999];
    flags[1] = (z2 == 0) ? 1 : 0;
}

// ---------------- degree histogram ----------------
__global__ __launch_bounds__(256) void edge_count_kernel(const int* __restrict__ ei,
                                                         const int* __restrict__ flags,
                                                         int* __restrict__ cnt) {
    int e = blockIdx.x * 256 + threadIdx.x;
    int d = flags[0] ? ei[2 * (N_EDGES + e)] : ei[N_EDGES + e];
    atomicAdd(&cnt[d], 1);
}

// ---------------- hierarchical scan ----------------
__global__ __launch_bounds__(256) void block_sum_kernel(const int* __restrict__ cnt,
                                                        int* __restrict__ bsum) {
    int idx = blockIdx.x * 256 + threadIdx.x;
    int v = (idx < N_NODES) ? cnt[idx] : 0;
    #pragma unroll
    for (int o = 32; o > 0; o >>= 1) v += __shfl_down(v, o, 64);
    __shared__ int s[4];
    if ((threadIdx.x & 63) == 0) s[threadIdx.x >> 6] = v;
    __syncthreads();
    if (threadIdx.x == 0) bsum[blockIdx.x] = s[0] + s[1] + s[2] + s[3];
}

__global__ __launch_bounds__(256) void scan_bsum_kernel(const int* __restrict__ bsum,
                                                        int* __restrict__ boff) {
    __shared__ int s[256];
    int t = threadIdx.x;
    int v = (t < SCAN_BLOCKS) ? bsum[t] : 0;
    s[t] = v;
    __syncthreads();
    #pragma unroll
    for (int o = 1; o < 256; o <<= 1) {
        int u = (t >= o) ? s[t - o] : 0;
        __syncthreads();
        s[t] += u;
        __syncthreads();
    }
    if (t < SCAN_BLOCKS) boff[t] = s[t] - v;   // exclusive
}

__global__ __launch_bounds__(256) void scan_fill_kernel(const int* __restrict__ cnt,
                                                        const int* __restrict__ boff,
                                                        int* __restrict__ row_ptr,
                                                        float* __restrict__ dis) {
    __shared__ int s[256];
    int t = threadIdx.x;
    int idx = blockIdx.x * 256 + t;
    int v = (idx < N_NODES) ? cnt[idx] : 0;
    s[t] = v;
    __syncthreads();
    #pragma unroll
    for (int o = 1; o < 256; o <<= 1) {
        int u = (t >= o) ? s[t - o] : 0;
        __syncthreads();
        s[t] += u;
        __syncthreads();
    }
    int excl = boff[blockIdx.x] + s[t] - v;
    if (idx < N_NODES) {
        row_ptr[idx] = excl;
        dis[idx] = 1.0f / sqrtf((float)v + 1.0f);
        if (idx == N_NODES - 1) row_ptr[N_NODES] = excl + v;
    }
}

// ---------------- CSR fill ----------------
__global__ __launch_bounds__(256) void csr_fill_kernel(const int* __restrict__ ei,
                                                       const int* __restrict__ flags,
                                                       const int* __restrict__ row_ptr,
                                                       int* __restrict__ cur,
                                                       const float* __restrict__ dis,
                                                       int2* __restrict__ recs) {
    int e = blockIdx.x * 256 + threadIdx.x;
    int f = flags[0];
    int s = f ? ei[2 * e] : ei[e];
    int d = f ? ei[2 * (N_EDGES + e)] : ei[N_EDGES + e];
    int pos = row_ptr[d] + atomicAdd(&cur[d], 1);
    float w = dis[s] * dis[d];
    recs[pos] = make_int2(s, __float_as_int(w));
}

// ---------------- graph_ptr ----------------
__global__ __launch_bounds__(512) void graph_ptr_kernel(const int* __restrict__ batch,
                                                        const int* __restrict__ flags,
                                                        int* __restrict__ gptr) {
    int t = threadIdx.x;
    if (t > N_GRAPHS) return;
    int f = flags[1];
    int lo = 0, hi = N_NODES;
    while (lo < hi) {
        int mid = (lo + hi) >> 1;
        int v = f ? batch[2 * mid] : batch[mid];
        if (v < t) lo = mid + 1; else hi = mid;
    }
    gptr[t] = lo;
}

// ---------------- W pack: f32 W[k][c] -> bf16 Wp[((ks*4+g)*256+c)*8+j] -------
// Fragment-ordered for mfma_16x16x32_bf16 B-operand: k = ks*32 + g*8 + j.
// Same (g,j)->k map as the A-fragment loads => dot-product is correct for ANY
// internal hw k-permutation (permutation-invariance of the k-sum).
__global__ __launch_bounds__(256) void pack_w_kernel(const float* __restrict__ W,
                                                     ushort* __restrict__ Wp) {
    int t = blockIdx.x * 256 + threadIdx.x;   // 65536 threads
    int k = t >> 8, c = t & 255;
    int ks = k >> 5, g = (k >> 3) & 3, j = k & 7;
    Wp[(((ks * 4 + g) * 256) + c) * 8 + j] = (ushort)bf16_rne(W[t]);
}

// ---------------- MFMA GEMM: out_bf[r][c] = bf16(sum_k A[r][k] W[k][c] + b[c])
// Block: 256 thr = 4 waves, 64 rows; wave = 16 rows x 256 cols (16 col-tiles).
// No LDS. B-frags from packed Wp (L2-resident, 256B coalesced segments).
// A_BF16=0: A is f32 (layer 1, x), convert in-register. =1: A is bf16 rows.
template <int A_BF16>
__global__ __launch_bounds__(256) void lin_mfma_kernel(const void* __restrict__ Aptr,
                                                       const ushort* __restrict__ Wp,
                                                       const float* __restrict__ bias,
                                                       ushort* __restrict__ out_bf) {
    int wave = threadIdx.x >> 6, lane = threadIdx.x & 63;
    int g = lane >> 4, cl = lane & 15;
    int arow = blockIdx.x * 64 + wave * 16 + cl;    // A row this lane supplies

    f32x4 acc00, acc01, acc02, acc03, acc04, acc05, acc06, acc07;
    f32x4 acc08, acc09, acc10, acc11, acc12, acc13, acc14, acc15;
    acc00=acc01=acc02=acc03=acc04=acc05=acc06=acc07=(f32x4){0.f,0.f,0.f,0.f};
    acc08=acc09=acc10=acc11=acc12=acc13=acc14=acc15=(f32x4){0.f,0.f,0.f,0.f};

    union frag_u { uint4 u; bf16x8 f; ushort us[8]; };

    #pragma unroll
    for (int ks = 0; ks < 8; ++ks) {
        frag_u fa;
        if (A_BF16) {
            const ushort* A = (const ushort*)Aptr;
            fa.u = (arow < N_NODES)
                ? *reinterpret_cast<const uint4*>(A + (size_t)arow * DIM + ks * 32 + g * 8)
                : make_uint4(0u, 0u, 0u, 0u);
        } else {
            const float* A = (const float*)Aptr;
            float4 v0, v1;
            if (arow < N_NODES) {
                const float* p = A + (size_t)arow * DIM + ks * 32 + g * 8;
                v0 = *reinterpret_cast<const float4*>(p);
                v1 = *reinterpret_cast<const float4*>(p + 4);
            } else {
                v0 = v1 = make_float4(0.f, 0.f, 0.f, 0.f);
            }
            fa.us[0] = (ushort)bf16_rne(v0.x); fa.us[1] = (ushort)bf16_rne(v0.y);
            fa.us[2] = (ushort)bf16_rne(v0.z); fa.us[3] = (ushort)bf16_rne(v0.w);
            fa.us[4] = (ushort)bf16_rne(v1.x); fa.us[5] = (ushort)bf16_rne(v1.y);
            fa.us[6] = (ushort)bf16_rne(v1.z); fa.us[7] = (ushort)bf16_rne(v1.w);
        }
        const ushort* bbase = Wp + ((size_t)(ks * 4 + g) * 256 + cl) * 8;
#define LIN_MMA(CT, ACC) { \
        frag_u fb; \
        fb.u = *reinterpret_cast<const uint4*>(bbase + (CT) * 16 * 8); \
        ACC = __builtin_amdgcn_mfma_f32_16x16x32_bf16(fa.f, fb.f, ACC, 0, 0, 0); }
        LIN_MMA(0, acc00)  LIN_MMA(1, acc01)  LIN_MMA(2, acc02)  LIN_MMA(3, acc03)
        LIN_MMA(4, acc04)  LIN_MMA(5, acc05)  LIN_MMA(6, acc06)  LIN_MMA(7, acc07)
        LIN_MMA(8, acc08)  LIN_MMA(9, acc09)  LIN_MMA(10, acc10) LIN_MMA(11, acc11)
        LIN_MMA(12, acc12) LIN_MMA(13, acc13) LIN_MMA(14, acc14) LIN_MMA(15, acc15)
#undef LIN_MMA
    }

    // C/D layout (HW-verified m89): col = lane&15, row = (lane>>4)*4 + i.
    int rbase = blockIdx.x * 64 + wave * 16 + g * 4;
#define LIN_ST(CT, ACC) { \
    float bb = bias[(CT) * 16 + cl]; \
    _Pragma("unroll") \
    for (int i = 0; i < 4; ++i) { \
        int r = rbase + i; \
        if (r < N_NODES) \
            out_bf[(size_t)r * DIM + (CT) * 16 + cl] = (ushort)bf16_rne(ACC[i] + bb); \
    } }
    LIN_ST(0, acc00)  LIN_ST(1, acc01)  LIN_ST(2, acc02)  LIN_ST(3, acc03)
    LIN_ST(4, acc04)  LIN_ST(5, acc05)  LIN_ST(6, acc06)  LIN_ST(7, acc07)
    LIN_ST(8, acc08)  LIN_ST(9, acc09)  LIN_ST(10, acc10) LIN_ST(11, acc11)
    LIN_ST(12, acc12) LIN_ST(13, acc13) LIN_ST(14, acc14) LIN_ST(15, acc15)
#undef LIN_ST
}

// ---------------- aggregation: one wave per destination node ----------------
// Gathers bf16 rows (512B), accumulates f32.
// LAYER==1: relu + exact-JAX dropout, writes bf16 (feeds MFMA lin2).
// LAYER==2: relu only, writes f32 (feeds pool).
template <int LAYER>
__global__ __launch_bounds__(256) void aggregate_kernel(const ushort* __restrict__ hb,
                                                        const int* __restrict__ row_ptr,
                                                        const int2* __restrict__ recs,
                                                        const float* __restrict__ dis,
                                                        const unsigned* __restrict__ mask,
                                                        float* __restrict__ outf,
                                                        ushort* __restrict__ outb) {
    int wave = threadIdx.x >> 6;
    int lane = threadIdx.x & 63;
    int node = blockIdx.x * 4 + wave;

    float dn = dis[node];
    float sw = dn * dn;
    uint2 s0 = reinterpret_cast<const uint2*>(hb + (size_t)node * DIM)[lane];
    float ax = sw * bf16_lo(s0.x), ay = sw * bf16_hi(s0.x);
    float az = sw * bf16_lo(s0.y), aw = sw * bf16_hi(s0.y);

    int p = row_ptr[node], e = row_ptr[node + 1];
    for (; p + 3 < e; p += 4) {
        int2 r0 = recs[p];
        int2 r1 = recs[p + 1];
        int2 r2 = recs[p + 2];
        int2 r3 = recs[p + 3];
        float w0 = __int_as_float(r0.y);
        float w1 = __int_as_float(r1.y);
        float w2 = __int_as_float(r2.y);
        float w3 = __int_as_float(r3.y);
        uint2 u0 = reinterpret_cast<const uint2*>(hb + (size_t)r0.x * DIM)[lane];
        uint2 u1 = reinterpret_cast<const uint2*>(hb + (size_t)r1.x * DIM)[lane];
        uint2 u2 = reinterpret_cast<const uint2*>(hb + (size_t)r2.x * DIM)[lane];
        uint2 u3 = reinterpret_cast<const uint2*>(hb + (size_t)r3.x * DIM)[lane];
        ax = fmaf(w0, bf16_lo(u0.x), ax); ay = fmaf(w0, bf16_hi(u0.x), ay);
        az = fmaf(w0, bf16_lo(u0.y), az); aw = fmaf(w0, bf16_hi(u0.y), aw);
        ax = fmaf(w1, bf16_lo(u1.x), ax); ay = fmaf(w1, bf16_hi(u1.x), ay);
        az = fmaf(w1, bf16_lo(u1.y), az); aw = fmaf(w1, bf16_hi(u1.y), aw);
        ax = fmaf(w2, bf16_lo(u2.x), ax); ay = fmaf(w2, bf16_hi(u2.x), ay);
        az = fmaf(w2, bf16_lo(u2.y), az); aw = fmaf(w2, bf16_hi(u2.y), aw);
        ax = fmaf(w3, bf16_lo(u3.x), ax); ay = fmaf(w3, bf16_hi(u3.x), ay);
        az = fmaf(w3, bf16_lo(u3.y), az); aw = fmaf(w3, bf16_hi(u3.y), aw);
    }
    for (; p < e; ++p) {
        int2 r0 = recs[p];
        float w0 = __int_as_float(r0.y);
        uint2 u = reinterpret_cast<const uint2*>(hb + (size_t)r0.x * DIM)[lane];
        ax = fmaf(w0, bf16_lo(u.x), ax); ay = fmaf(w0, bf16_hi(u.x), ay);
        az = fmaf(w0, bf16_lo(u.y), az); aw = fmaf(w0, bf16_hi(u.y), aw);
    }

    ax = fmaxf(ax, 0.f); ay = fmaxf(ay, 0.f);
    az = fmaxf(az, 0.f); aw = fmaxf(aw, 0.f);

    if (LAYER == 1) {
        unsigned w = mask[node * 8 + (lane >> 3)];
        int b = (lane & 7) * 4;
        ax = ((w >> (b + 0)) & 1u) ? ax * 2.0f : 0.0f;
        ay = ((w >> (b + 1)) & 1u) ? ay * 2.0f : 0.0f;
        az = ((w >> (b + 2)) & 1u) ? az * 2.0f : 0.0f;
        aw = ((w >> (b + 3)) & 1u) ? aw * 2.0f : 0.0f;
        reinterpret_cast<uint2*>(outb + (size_t)node * DIM)[lane] =
            make_uint2(bf16_pack2(ax, ay), bf16_pack2(az, aw));
    } else {
        reinterpret_cast<float4*>(outf + (size_t)node * DIM)[lane] =
            make_float4(ax, ay, az, aw);
    }
}

// ---------------- mean pooling over sorted batch segments ----------------
__global__ __launch_bounds__(64) void pool_kernel(const float* __restrict__ h,
                                                  const int* __restrict__ gptr,
                                                  float* __restrict__ out) {
    int g = blockIdx.x >> 2;
    int c = blockIdx.x & 3;
    int lane = threadIdx.x;
    int col = c * 64 + lane;
    int s = gptr[g], e = gptr[g + 1];
    float a0 = 0.f, a1 = 0.f, a2 = 0.f, a3 = 0.f;
    int n = s;
    for (; n + 3 < e; n += 4) {
        a0 += h[(size_t)n * DIM + col];
        a1 += h[(size_t)(n + 1) * DIM + col];
        a2 += h[(size_t)(n + 2) * DIM + col];
        a3 += h[(size_t)(n + 3) * DIM + col];
    }
    for (; n < e; ++n) a0 += h[(size_t)n * DIM + col];
    float sum = (a0 + a1) + (a2 + a3);
    out[g * DIM + col] = sum / fmaxf((float)(e - s), 1.0f);
}

// ---------------- launch ----------------
extern "C" void kernel_launch(void* const* d_in, const int* in_sizes, int n_in,
                              void* d_out, int out_size, void* d_ws, size_t ws_size,
                              hipStream_t stream) {
    const float* x     = (const float*)d_in[0];
    const int*   ei    = (const int*)d_in[1];       // [2][N_EDGES] (int32 or int64)
    const int*   batch = (const int*)d_in[2];
    const float* W1    = (const float*)d_in[3];
    const float* b1    = (const float*)d_in[4];
    const float* W2    = (const float*)d_in[5];
    const float* b2    = (const float*)d_in[6];
    float*       out   = (float*)d_out;

    // workspace carve-up (256B aligned)
    char* Wp = (char*)d_ws;
    size_t off = 0;
    auto take = [&](size_t bytes) -> char* {
        char* p = Wp + off;
        off += (bytes + 255) & ~(size_t)255;
        return p;
    };
    int*      cnt    = (int*)take((size_t)N_NODES * 4);
    int*      cur    = (int*)take((size_t)N_NODES * 4);
    int*      rowptr = (int*)take((size_t)(N_NODES + 1) * 4);
    float*    dis    = (float*)take((size_t)N_NODES * 4);
    int2*     recs   = (int2*)take((size_t)N_EDGES * 8);
    int*      gptr   = (int*)take((size_t)(N_GRAPHS + 1) * 4);
    unsigned* mask   = (unsigned*)take((size_t)MASK_WORDS * 4);
    int*      flags  = (int*)take(256);
    int*      bsum   = (int*)take((size_t)SCAN_BLOCKS * 4);
    int*      boff   = (int*)take((size_t)(SCAN_BLOCKS + 1) * 4);
    ushort*   wp1    = (ushort*)take((size_t)DIM * DIM * 2);       // packed bf16 W1
    ushort*   wp2    = (ushort*)take((size_t)DIM * DIM * 2);       // packed bf16 W2
    ushort*   hbf    = (ushort*)take((size_t)N_NODES * DIM * 2);   // lin out (bf16)
    ushort*   a1bf   = (ushort*)take((size_t)N_NODES * DIM * 2);   // agg1 out (bf16)
    float*    bufB   = (float*)take((size_t)N_NODES * DIM * 4);    // agg2 out (f32)
    (void)ws_size; (void)in_sizes; (void)n_in; (void)out_size;

    // zero the two atomic-counter arrays (cnt, cur are adjacent)
    hipMemsetAsync(cnt, 0, (size_t)((char*)rowptr - (char*)cnt), stream);

    // independent: dropout mask + packed weights
    mask_kernel<<<(MASK_WORDS + 255) / 256, 256, 0, stream>>>(mask);
    pack_w_kernel<<<(DIM * DIM) / 256, 256, 0, stream>>>(W1, wp1);
    pack_w_kernel<<<(DIM * DIM) / 256, 256, 0, stream>>>(W2, wp2);

    // input dtype-delivery detection, then graph structure
    detect_kernel<<<1, 64, 0, stream>>>(ei, batch, flags);
    edge_count_kernel<<<N_EDGES / 256, 256, 0, stream>>>(ei, flags, cnt);
    block_sum_kernel<<<SCAN_BLOCKS, 256, 0, stream>>>(cnt, bsum);
    scan_bsum_kernel<<<1, 256, 0, stream>>>(bsum, boff);
    scan_fill_kernel<<<SCAN_BLOCKS, 256, 0, stream>>>(cnt, boff, rowptr, dis);
    csr_fill_kernel<<<N_EDGES / 256, 256, 0, stream>>>(ei, flags, rowptr, cur, dis, recs);
    graph_ptr_kernel<<<1, 512, 0, stream>>>(batch, flags, gptr);

    const int lin_grid = (N_NODES + 63) / 64;   // 782

    // layer 1: MFMA lin (f32 A) -> bf16 h, aggregate -> bf16 a1
    lin_mfma_kernel<0><<<lin_grid, 256, 0, stream>>>(x, wp1, b1, hbf);
    aggregate_kernel<1><<<N_NODES / 4, 256, 0, stream>>>(hbf, rowptr, recs, dis, mask,
                                                         nullptr, a1bf);

    // layer 2: MFMA lin (bf16 A) -> bf16 h, aggregate -> f32
    lin_mfma_kernel<1><<<lin_grid, 256, 0, stream>>>(a1bf, wp2, b2, hbf);
    aggregate_kernel<2><<<N_NODES / 4, 256, 0, stream>>>(hbf, rowptr, recs, dis, mask,
                                                         bufB, nullptr);

    // pooling
    pool_kernel<<<N_GRAPHS * 4, 64, 0, stream>>>(bufB, gptr, out);
}